// Round 3
// baseline (600.862 us; speedup 1.0000x reference)
//
#include <hip/hip_runtime.h>
#include <stdint.h>

// Problem constants (from reference setup_inputs): B,H,T,S,D
#define B_ 2
#define H_ 16
#define T_ 2048
#define S_ 2048
#define D_ 128

typedef float f32x4 __attribute__((ext_vector_type(4)));

// ---------------------------------------------------------------------------
// Kernel 0: clear the two amax slots (replaces hipMemsetAsync in the graph)
__global__ void init_kernel(unsigned* __restrict__ amax_bits) {
  if (threadIdx.x < 2) amax_bits[threadIdx.x] = 0u;
}

// ---------------------------------------------------------------------------
// Kernel 1: abs-max reduction (uint-bit atomicMax; valid since |x| >= 0)
__global__ void amax_kernel(const float* __restrict__ x, long n4,
                            unsigned* __restrict__ out) {
  const f32x4* x4 = (const f32x4*)x;
  long i      = (long)blockIdx.x * blockDim.x + threadIdx.x;
  long stride = (long)gridDim.x * blockDim.x;
  float m = 0.0f;
  for (; i < n4; i += stride) {
    f32x4 v = x4[i];
    m = fmaxf(m, fmaxf(fmaxf(fabsf(v[0]), fabsf(v[1])),
                       fmaxf(fabsf(v[2]), fabsf(v[3]))));
  }
  #pragma unroll
  for (int off = 32; off; off >>= 1) m = fmaxf(m, __shfl_xor(m, off, 64));
  if ((threadIdx.x & 63) == 0) atomicMax(out, __float_as_uint(m));
}

// ---------------------------------------------------------------------------
// HW e4m3fn quantization helpers (v_cvt_pk_fp8_f32 is RNE, OCP on gfx950).
__device__ __forceinline__ float clamp448(float y) {
  return fminf(fmaxf(y, -448.0f), 448.0f);
}

__device__ __forceinline__ unsigned pack_fp8x4(float a, float b, float c,
                                               float d) {
  int w = 0;
  w = __builtin_amdgcn_cvt_pk_fp8_f32(a, b, w, false);
  w = __builtin_amdgcn_cvt_pk_fp8_f32(c, d, w, true);
  return (unsigned)w;
}

__device__ __forceinline__ long pack_fp8x8(const float* f) {
  unsigned d0 = pack_fp8x4(f[0], f[1], f[2], f[3]);
  unsigned d1 = pack_fp8x4(f[4], f[5], f[6], f[7]);
  return (long)(((unsigned long long)d1 << 32) | d0);
}

// ---------------------------------------------------------------------------
// Kernel 2a: quantize A -> Aq e4m3 bytes, same layout. Pure coalesced stream:
// each thread 4 floats in (16 B), 4 bytes out.
__global__ void quanta_kernel(const float* __restrict__ a,
                              unsigned* __restrict__ aq, long n4,
                              const unsigned* __restrict__ amax_bits) {
  float amax = fmaxf(__uint_as_float(amax_bits[0]), 1e-12f);
  float inv  = 448.0f / amax;
  const f32x4* a4 = (const f32x4*)a;
  long i      = (long)blockIdx.x * blockDim.x + threadIdx.x;
  long stride = (long)gridDim.x * blockDim.x;
  for (; i < n4; i += stride) {
    f32x4 x = a4[i];
    aq[i] = pack_fp8x4(clamp448(x[0] * inv), clamp448(x[1] * inv),
                       clamp448(x[2] * inv), clamp448(x[3] * inv));
  }
}

// ---------------------------------------------------------------------------
// Kernel 2b: quantize v to e4m3 bytes + transpose -> Vt[bh][d][s]  (8 MB)
// grid: 32 bh * 64 s-chunks of 32; block 256 = 128 d * 2 s-halves of 16
__global__ void quantv_kernel(const float* __restrict__ v,
                              unsigned char* __restrict__ vt,
                              const unsigned* __restrict__ amax_bits) {
  float amax = fmaxf(__uint_as_float(amax_bits[1]), 1e-12f);
  float inv  = 448.0f / amax;
  int bid = blockIdx.x;
  int bh  = bid >> 6;
  int s0  = (bid & 63) * 32;
  int d   = threadIdx.x & 127;
  int h2  = threadIdx.x >> 7;          // 0,1
  const float*   vb  = v  + (size_t)bh * S_ * D_;
  unsigned char* vtb = vt + (size_t)bh * D_ * S_;
  unsigned dw[4];
  #pragma unroll
  for (int q = 0; q < 4; ++q) {
    float f[4];
    #pragma unroll
    for (int j = 0; j < 4; ++j)
      f[j] = clamp448(vb[(size_t)(s0 + h2 * 16 + q * 4 + j) * D_ + d] * inv);
    dw[q] = pack_fp8x4(f[0], f[1], f[2], f[3]);
  }
  *(uint4*)(vtb + (size_t)d * S_ + s0 + h2 * 16) = *(const uint4*)dw;
}

// ---------------------------------------------------------------------------
// Kernel 3: GEMM on pre-quantized fp8:  C[t,d] = (sum_s Aq*Vq) * scale
// 1024 blocks: (bh, t-tile of 64). 4 waves, 16 rows each, full D=128.
// No LDS/barriers; explicit 1-deep register double-buffer so vmcnt never
// drains: next k-step's 9 fragment loads are in flight during current MFMAs.
__global__ __launch_bounds__(256, 4)
void gemm_q_kernel(const unsigned char* __restrict__ Aq,
                   const unsigned char* __restrict__ Vt,
                   float* __restrict__ out,
                   const unsigned* __restrict__ amax_bits) {
  float amax_a = fmaxf(__uint_as_float(amax_bits[0]), 1e-12f);
  float amax_v = fmaxf(__uint_as_float(amax_bits[1]), 1e-12f);
  float out_scale = (amax_a / 448.0f) * (amax_v / 448.0f);

  int bid  = blockIdx.x;
  int bh   = bid >> 5;                 // 0..31
  int t0   = (bid & 31) * 64;
  int b    = bh >> 4;                  // H_=16
  int h    = bh & 15;

  int wave = threadIdx.x >> 6;         // 0..3 -> rows [t0+16w, +16)
  int lane = threadIdx.x & 63;
  int lr   = lane & 15;                // A row-in-frag / B col / C col
  int kg   = lane >> 4;                // k-group (k = kg*8 + j)

  const unsigned char* arow =
      Aq + (size_t)bh * T_ * S_ + (size_t)(t0 + wave * 16 + lr) * S_;
  const unsigned char* vrow = Vt + (size_t)bh * D_ * S_ + (size_t)lr * S_;

  f32x4 acc[8];
  #pragma unroll
  for (int j = 0; j < 8; ++j) acc[j] = (f32x4)0.0f;

  // prologue: fragments for ks=0
  long a_cur = *(const long*)(arow + kg * 8);
  long b_cur[8];
  #pragma unroll
  for (int ni = 0; ni < 8; ++ni)
    b_cur[ni] = *(const long*)(vrow + (size_t)ni * 16 * S_ + kg * 8);

  for (int ks = 0; ks < S_ / 32; ++ks) {
    // issue next k-step's loads (clamped on last iter: redundant, harmless)
    int ksn = (ks + 1 < S_ / 32) ? ks + 1 : ks;
    int kbn = ksn * 32 + kg * 8;
    long a_nxt = *(const long*)(arow + kbn);
    long b_nxt[8];
    #pragma unroll
    for (int ni = 0; ni < 8; ++ni)
      b_nxt[ni] = *(const long*)(vrow + (size_t)ni * 16 * S_ + kbn);

    #pragma unroll
    for (int ni = 0; ni < 8; ++ni)
      acc[ni] = __builtin_amdgcn_mfma_f32_16x16x32_fp8_fp8(
          a_cur, b_cur[ni], acc[ni], 0, 0, 0);

    a_cur = a_nxt;
    #pragma unroll
    for (int ni = 0; ni < 8; ++ni) b_cur[ni] = b_nxt[ni];
  }

  // ---- epilogue: C/D layout col=lane&15, row=(lane>>4)*4+r  [guide §3, m89]
  // out[b][t][h][d], d = ni*16+lr, t = t0 + wave*16 + kg*4 + r
  float* ob = out + (size_t)b * T_ * H_ * D_ + (size_t)h * D_;
  int trow = t0 + wave * 16;
  #pragma unroll
  for (int ni = 0; ni < 8; ++ni) {
    int d = ni * 16 + lr;
    #pragma unroll
    for (int r = 0; r < 4; ++r) {
      int t = trow + kg * 4 + r;
      ob[(size_t)t * H_ * D_ + d] = acc[ni][r] * out_scale;
    }
  }
}

// ---------------------------------------------------------------------------
// Fallback (tiny d_ws): fused in-register quant GEMM, f32 A + f32 V direct.
__global__ __launch_bounds__(256, 4)
void gemm_fused_kernel(const float* __restrict__ A,
                       const float* __restrict__ Vf, float* __restrict__ out,
                       const unsigned* __restrict__ amax_bits) {
  float amax_a = fmaxf(__uint_as_float(amax_bits[0]), 1e-12f);
  float amax_v = fmaxf(__uint_as_float(amax_bits[1]), 1e-12f);
  float inv_a  = 448.0f / amax_a;
  float inv_v  = 448.0f / amax_v;
  float out_scale = (amax_a / 448.0f) * (amax_v / 448.0f);

  int bid  = blockIdx.x;
  int bh   = bid >> 5;
  int t0   = (bid & 31) * 64;
  int b    = bh >> 4;
  int h    = bh & 15;
  int wave = threadIdx.x >> 6;
  int lane = threadIdx.x & 63;
  int lr   = lane & 15;
  int kg   = lane >> 4;

  const float* arow =
      A + (size_t)bh * T_ * S_ + (size_t)(t0 + wave * 16 + lr) * S_;
  const float* vfb = Vf + (size_t)bh * S_ * D_;

  f32x4 acc[8];
  #pragma unroll
  for (int j = 0; j < 8; ++j) acc[j] = (f32x4)0.0f;

  for (int ks = 0; ks < S_ / 32; ++ks) {
    int kb = ks * 32 + kg * 8;
    long bfrag[8];
    #pragma unroll
    for (int ni = 0; ni < 8; ++ni) {
      float f[8];
      #pragma unroll
      for (int j = 0; j < 8; ++j)
        f[j] = clamp448(vfb[(size_t)(kb + j) * D_ + ni * 16 + lr] * inv_v);
      bfrag[ni] = pack_fp8x8(f);
    }
    f32x4 x0 = *(const f32x4*)(arow + kb);
    f32x4 x1 = *(const f32x4*)(arow + kb + 4);
    float f[8];
    #pragma unroll
    for (int j = 0; j < 4; ++j) {
      f[j]     = clamp448(x0[j] * inv_a);
      f[j + 4] = clamp448(x1[j] * inv_a);
    }
    long afrag = pack_fp8x8(f);
    #pragma unroll
    for (int ni = 0; ni < 8; ++ni)
      acc[ni] = __builtin_amdgcn_mfma_f32_16x16x32_fp8_fp8(
          afrag, bfrag[ni], acc[ni], 0, 0, 0);
  }

  float* ob = out + (size_t)b * T_ * H_ * D_ + (size_t)h * D_;
  int trow = t0 + wave * 16;
  #pragma unroll
  for (int ni = 0; ni < 8; ++ni) {
    int d = ni * 16 + lr;
    #pragma unroll
    for (int r = 0; r < 4; ++r) {
      int t = trow + kg * 4 + r;
      ob[(size_t)t * H_ * D_ + d] = acc[ni][r] * out_scale;
    }
  }
}

// ---------------------------------------------------------------------------
extern "C" void kernel_launch(void* const* d_in, const int* in_sizes, int n_in,
                              void* d_out, int out_size, void* d_ws, size_t ws_size,
                              hipStream_t stream) {
  const float* aw = (const float*)d_in[0];
  const float* v  = (const float*)d_in[1];
  float* out      = (float*)d_out;

  unsigned*      amax_bits = (unsigned*)d_ws;
  unsigned char* vt        = (unsigned char*)d_ws + 256;
  size_t vt_bytes = (size_t)B_ * H_ * D_ * S_;                  // 8 MB
  unsigned char* aqp       = (unsigned char*)d_ws + 256 + vt_bytes;
  size_t aq_bytes = (size_t)B_ * H_ * T_ * S_;                  // 134 MB
  size_t need_full = 256 + vt_bytes + aq_bytes;

  init_kernel<<<1, 64, 0, stream>>>(amax_bits);

  long n4a = (long)B_ * H_ * T_ * S_ / 4;
  long n4v = (long)B_ * H_ * S_ * D_ / 4;
  amax_kernel<<<2048, 256, 0, stream>>>(aw, n4a, amax_bits + 0);
  amax_kernel<<<512,  256, 0, stream>>>(v,  n4v, amax_bits + 1);

  if (ws_size >= need_full) {
    quanta_kernel<<<2048, 256, 0, stream>>>(aw, (unsigned*)aqp, n4a,
                                            amax_bits);
    quantv_kernel<<<32 * 64, 256, 0, stream>>>(v, vt, amax_bits);
    gemm_q_kernel<<<B_ * H_ * (T_ / 64), 256, 0, stream>>>(aqp, vt, out,
                                                           amax_bits);
  } else {
    gemm_fused_kernel<<<B_ * H_ * (T_ / 64), 256, 0, stream>>>(aw, v, out,
                                                               amax_bits);
  }
}

// Round 4
// 565.421 us; speedup vs baseline: 1.0627x; 1.0627x over previous
//
#include <hip/hip_runtime.h>
#include <stdint.h>

// Problem constants (from reference setup_inputs): B,H,T,S,D
#define B_ 2
#define H_ 16
#define T_ 2048
#define S_ 2048
#define D_ 128
#define BH_ (B_ * H_)              // 32
#define NTB (T_ / 16)              // 128 row-tiles per bh
#define NKS (S_ / 32)              // 64 k-slots per bh
#define ATILE_B 512                // bytes per (tb,ks) A fragment tile
#define APANEL_B (NKS * ATILE_B)   // 32 KB per (bh,tb)
#define VKS_B (D_ * 32)            // 4 KB per (bh,ks)
#define SLAB_KS 8
#define SLAB_B (SLAB_KS * VKS_B)   // 32 KB LDS slab

typedef float f32x4 __attribute__((ext_vector_type(4)));

// ---------------------------------------------------------------------------
// Kernel 0: clear the two amax slots (replaces hipMemsetAsync in the graph)
__global__ void init_kernel(unsigned* __restrict__ amax_bits) {
  if (threadIdx.x < 2) amax_bits[threadIdx.x] = 0u;
}

// ---------------------------------------------------------------------------
// Kernel 1: abs-max of A and V in one dispatch (blocks <2048 -> A, rest -> V)
__global__ void amax2_kernel(const float* __restrict__ a, long n4a,
                             const float* __restrict__ v, long n4v,
                             unsigned* __restrict__ out) {
  const f32x4* x4;
  long n4, i, stride;
  unsigned* dst;
  if (blockIdx.x < 2048) {
    x4 = (const f32x4*)a;  n4 = n4a;  dst = out;
    i = (long)blockIdx.x * blockDim.x + threadIdx.x;
    stride = 2048L * blockDim.x;
  } else {
    x4 = (const f32x4*)v;  n4 = n4v;  dst = out + 1;
    i = (long)(blockIdx.x - 2048) * blockDim.x + threadIdx.x;
    stride = 256L * blockDim.x;
  }
  float m = 0.0f;
  for (; i < n4; i += stride) {
    f32x4 val = x4[i];
    m = fmaxf(m, fmaxf(fmaxf(fabsf(val[0]), fabsf(val[1])),
                       fmaxf(fabsf(val[2]), fabsf(val[3]))));
  }
  #pragma unroll
  for (int off = 32; off; off >>= 1) m = fmaxf(m, __shfl_xor(m, off, 64));
  if ((threadIdx.x & 63) == 0) atomicMax(dst, __float_as_uint(m));
}

// ---------------------------------------------------------------------------
// HW e4m3fn quantization helpers (v_cvt_pk_fp8_f32 is RNE, OCP on gfx950).
__device__ __forceinline__ float clamp448(float y) {
  return fminf(fmaxf(y, -448.0f), 448.0f);
}

__device__ __forceinline__ unsigned pack_fp8x4(float a, float b, float c,
                                               float d) {
  int w = 0;
  w = __builtin_amdgcn_cvt_pk_fp8_f32(a, b, w, false);
  w = __builtin_amdgcn_cvt_pk_fp8_f32(c, d, w, true);
  return (unsigned)w;
}

__device__ __forceinline__ long pack_fp8x8(const float* f) {
  unsigned d0 = pack_fp8x4(f[0], f[1], f[2], f[3]);
  unsigned d1 = pack_fp8x4(f[4], f[5], f[6], f[7]);
  return (long)(((unsigned long long)d1 << 32) | d0);
}

// ---------------------------------------------------------------------------
// Kernel 2a: quantize A into MFMA-fragment-major tiles.
// Aq_t[bh][tb][ks][ (kg*16+lr)*8 + j ] = q(A[bh][tb*16+lr][ks*32+kg*8+j])
// Block = one (bh,tb): reads 16 rows x 2048 f32 (dense), writes 32 KB tile.
// Thread t handles slot (ks=t>>2, kg=t&3) for every row i: one 8-B store each.
__global__ void quanta_tiled_kernel(const float* __restrict__ A,
                                    unsigned char* __restrict__ Aq,
                                    const unsigned* __restrict__ amax_bits) {
  float amax = fmaxf(__uint_as_float(amax_bits[0]), 1e-12f);
  float inv  = 448.0f / amax;
  int bh = blockIdx.x >> 7;          // grid = 32*128
  int tb = blockIdx.x & 127;
  const float*   abase = A  + ((size_t)bh * T_ + (size_t)tb * 16) * S_;
  unsigned char* obase = Aq + ((size_t)bh * NTB + tb) * APANEL_B;
  int t  = threadIdx.x;
  int ks = t >> 2, kg = t & 3;
  unsigned char* oslot = obase + ks * ATILE_B + kg * 16 * 8;
  #pragma unroll 4
  for (int i = 0; i < 16; ++i) {     // row within tile (= lr)
    const float* rp = abase + (size_t)i * S_ + t * 8;
    f32x4 x0 = *(const f32x4*)rp;
    f32x4 x1 = *(const f32x4*)(rp + 4);
    uint2 w;
    w.x = pack_fp8x4(clamp448(x0[0] * inv), clamp448(x0[1] * inv),
                     clamp448(x0[2] * inv), clamp448(x0[3] * inv));
    w.y = pack_fp8x4(clamp448(x1[0] * inv), clamp448(x1[1] * inv),
                     clamp448(x1[2] * inv), clamp448(x1[3] * inv));
    *(uint2*)(oslot + i * 8) = w;
  }
}

// ---------------------------------------------------------------------------
// Kernel 2b: quantize V -> Vq[bh][ks][d][j], j = s&31 (fragment-major, so a
// BK=256 slab is 32 KB contiguous). Block = one (bh,ks): 32 s-rows x 128 d.
__global__ void quantv_tiled_kernel(const float* __restrict__ V,
                                    unsigned char* __restrict__ Vq,
                                    const unsigned* __restrict__ amax_bits) {
  float amax = fmaxf(__uint_as_float(amax_bits[1]), 1e-12f);
  float inv  = 448.0f / amax;
  int bh = blockIdx.x >> 6;          // grid = 32*64
  int ks = blockIdx.x & 63;
  const float*   vb = V  + ((size_t)bh * S_ + (size_t)ks * 32) * D_;
  unsigned char* ob = Vq + ((size_t)bh * NKS + ks) * VKS_B;
  int d  = threadIdx.x & 127;
  int sh = threadIdx.x >> 7;         // 0,1 (s-halves of 16)
  unsigned dw[4];
  #pragma unroll
  for (int q = 0; q < 4; ++q) {
    float f[4];
    #pragma unroll
    for (int j = 0; j < 4; ++j)
      f[j] = clamp448(vb[(size_t)(sh * 16 + q * 4 + j) * D_ + d] * inv);
    dw[q] = pack_fp8x4(f[0], f[1], f[2], f[3]);
  }
  *(uint4*)(ob + d * 32 + sh * 16) = *(const uint4*)dw;
}

// ---------------------------------------------------------------------------
// Kernel 3: GEMM on fragment-major fp8. Block = 4 waves, 64x128 C-tile.
// All global loads dense 512-B wave transactions; B slab (32 KB, BK=256)
// reg-staged into LDS once, reused by all 4 waves; slab kt+1 prefetched into
// registers during compute of slab kt (T14). XCD-bijective block swizzle.
__global__ __launch_bounds__(256, 4)
void gemm_tiled_kernel(const unsigned char* __restrict__ Aq,
                       const unsigned char* __restrict__ Vq,
                       float* __restrict__ out,
                       const unsigned* __restrict__ amax_bits) {
  __shared__ unsigned char sB[SLAB_B];

  float amax_a = fmaxf(__uint_as_float(amax_bits[0]), 1e-12f);
  float amax_v = fmaxf(__uint_as_float(amax_bits[1]), 1e-12f);
  float out_scale = (amax_a / 448.0f) * (amax_v / 448.0f);

  int bid = blockIdx.x;                      // 1024 blocks, 1024%8==0
  int swz = (bid & 7) * 128 + (bid >> 3);    // contiguous chunk per XCD (T1)
  int bh  = swz >> 5;
  int tbb = swz & 31;                        // 64-row block tile

  int w    = threadIdx.x >> 6;               // wave 0..3
  int lane = threadIdx.x & 63;
  int lr   = lane & 15;
  int kg   = lane >> 4;

  const unsigned char* apanel =
      Aq + ((size_t)bh * NTB + (tbb * 4 + w)) * APANEL_B;
  const uint4* vpanel = (const uint4*)(Vq + (size_t)bh * NKS * VKS_B);
  uint4* sB4 = (uint4*)sB;
  int tid = threadIdx.x;

  f32x4 acc[8];
  #pragma unroll
  for (int j = 0; j < 8; ++j) acc[j] = (f32x4)0.0f;

  // prefetch slab 0 into registers
  uint4 st[8];
  #pragma unroll
  for (int si = 0; si < 8; ++si) st[si] = vpanel[si * 256 + tid];

  for (int kt = 0; kt < NKS / SLAB_KS; ++kt) {   // 8 slabs of BK=256
    __syncthreads();                              // prev compute done
    #pragma unroll
    for (int si = 0; si < 8; ++si) sB4[si * 256 + tid] = st[si];
    // issue next slab's loads; latency hides under this slab's compute
    int ktn = (kt + 1 < NKS / SLAB_KS) ? kt + 1 : kt;
    #pragma unroll
    for (int si = 0; si < 8; ++si)
      st[si] = vpanel[(size_t)ktn * 256 * 8 + si * 256 + tid];
    __syncthreads();                              // slab visible

    #pragma unroll
    for (int ks = 0; ks < SLAB_KS; ++ks) {
      long afrag =
          *(const long*)(apanel + (size_t)(kt * SLAB_KS + ks) * ATILE_B +
                         lane * 8);                         // dense 512 B/wave
      #pragma unroll
      for (int ni = 0; ni < 8; ++ni) {
        long bfrag =
            *(const long*)(sB + ks * VKS_B + (ni * 16 + lr) * 32 + kg * 8);
        acc[ni] = __builtin_amdgcn_mfma_f32_16x16x32_fp8_fp8(afrag, bfrag,
                                                             acc[ni], 0, 0, 0);
      }
    }
  }

  // ---- epilogue: C/D layout col=lane&15, row=(lane>>4)*4+r  [guide §3, m89]
  // out[b][t][h][d], d = ni*16+lr, t = (tbb*4+w)*16 + kg*4 + r
  int b = bh >> 4, h = bh & 15;
  float* ob = out + (size_t)b * T_ * (H_ * D_) + (size_t)h * D_;
  int trow = (tbb * 4 + w) * 16;
  #pragma unroll
  for (int ni = 0; ni < 8; ++ni) {
    int d = ni * 16 + lr;
    #pragma unroll
    for (int r = 0; r < 4; ++r) {
      int t = trow + kg * 4 + r;
      ob[(size_t)t * (H_ * D_) + d] = acc[ni][r] * out_scale;
    }
  }
}

// ---------------------------------------------------------------------------
// Fallback (tiny d_ws): fused in-register quant GEMM, f32 A + f32 V direct.
__global__ __launch_bounds__(256, 4)
void gemm_fused_kernel(const float* __restrict__ A,
                       const float* __restrict__ Vf, float* __restrict__ out,
                       const unsigned* __restrict__ amax_bits) {
  float amax_a = fmaxf(__uint_as_float(amax_bits[0]), 1e-12f);
  float amax_v = fmaxf(__uint_as_float(amax_bits[1]), 1e-12f);
  float inv_a  = 448.0f / amax_a;
  float inv_v  = 448.0f / amax_v;
  float out_scale = (amax_a / 448.0f) * (amax_v / 448.0f);

  int bid  = blockIdx.x;
  int bh   = bid >> 5;
  int t0   = (bid & 31) * 64;
  int b    = bh >> 4;
  int h    = bh & 15;
  int wave = threadIdx.x >> 6;
  int lane = threadIdx.x & 63;
  int lr   = lane & 15;
  int kg   = lane >> 4;

  const float* arow =
      A + (size_t)bh * T_ * S_ + (size_t)(t0 + wave * 16 + lr) * S_;
  const float* vfb = Vf + (size_t)bh * S_ * D_;

  f32x4 acc[8];
  #pragma unroll
  for (int j = 0; j < 8; ++j) acc[j] = (f32x4)0.0f;

  for (int ks = 0; ks < S_ / 32; ++ks) {
    int kb = ks * 32 + kg * 8;
    long bfrag[8];
    #pragma unroll
    for (int ni = 0; ni < 8; ++ni) {
      float f[8];
      #pragma unroll
      for (int j = 0; j < 8; ++j)
        f[j] = clamp448(vfb[(size_t)(kb + j) * D_ + ni * 16 + lr] * inv_v);
      bfrag[ni] = pack_fp8x8(f);
    }
    f32x4 x0 = *(const f32x4*)(arow + kb);
    f32x4 x1 = *(const f32x4*)(arow + kb + 4);
    float f[8];
    #pragma unroll
    for (int j = 0; j < 4; ++j) {
      f[j]     = clamp448(x0[j] * inv_a);
      f[j + 4] = clamp448(x1[j] * inv_a);
    }
    long afrag = pack_fp8x8(f);
    #pragma unroll
    for (int ni = 0; ni < 8; ++ni)
      acc[ni] = __builtin_amdgcn_mfma_f32_16x16x32_fp8_fp8(afrag, bfrag[ni],
                                                           acc[ni], 0, 0, 0);
  }

  float* ob = out + (size_t)b * T_ * H_ * D_ + (size_t)h * D_;
  int trow = t0 + wave * 16;
  #pragma unroll
  for (int ni = 0; ni < 8; ++ni) {
    int d = ni * 16 + lr;
    #pragma unroll
    for (int r = 0; r < 4; ++r) {
      int t = trow + kg * 4 + r;
      ob[(size_t)t * H_ * D_ + d] = acc[ni][r] * out_scale;
    }
  }
}

// ---------------------------------------------------------------------------
extern "C" void kernel_launch(void* const* d_in, const int* in_sizes, int n_in,
                              void* d_out, int out_size, void* d_ws, size_t ws_size,
                              hipStream_t stream) {
  const float* aw = (const float*)d_in[0];
  const float* v  = (const float*)d_in[1];
  float* out      = (float*)d_out;

  unsigned*      amax_bits = (unsigned*)d_ws;
  unsigned char* vq        = (unsigned char*)d_ws + 256;
  size_t vq_bytes = (size_t)BH_ * NKS * VKS_B;            // 8 MB
  unsigned char* aq        = vq + vq_bytes;
  size_t aq_bytes = (size_t)BH_ * NTB * APANEL_B;         // 134 MB
  size_t need_full = 256 + vq_bytes + aq_bytes;

  init_kernel<<<1, 64, 0, stream>>>(amax_bits);

  long n4a = (long)B_ * H_ * T_ * S_ / 4;
  long n4v = (long)B_ * H_ * S_ * D_ / 4;
  amax2_kernel<<<2304, 256, 0, stream>>>(aw, n4a, v, n4v, amax_bits);

  if (ws_size >= need_full) {
    quanta_tiled_kernel<<<BH_ * NTB, 256, 0, stream>>>(aw, aq, amax_bits);
    quantv_tiled_kernel<<<BH_ * NKS, 256, 0, stream>>>(v, vq, amax_bits);
    gemm_tiled_kernel<<<BH_ * 32, 256, 0, stream>>>(aq, vq, out, amax_bits);
  } else {
    gemm_fused_kernel<<<B_ * H_ * (T_ / 64), 256, 0, stream>>>(aw, v, out,
                                                               amax_bits);
  }
}

// Round 6
// 353.899 us; speedup vs baseline: 1.6978x; 1.5977x over previous
//
#include <hip/hip_runtime.h>
#include <stdint.h>

// Problem constants (from reference setup_inputs): B,H,T,S,D
#define B_ 2
#define H_ 16
#define T_ 2048
#define S_ 2048
#define D_ 128
#define BH_ (B_ * H_)              // 32
#define NKS (S_ / 32)              // 64 k-slots of 32 per bh
#define VKS_B (D_ * 32)            // 4 KB per (bh,ks) fp8 V tile

typedef float f32x4 __attribute__((ext_vector_type(4)));

// ---------------------------------------------------------------------------
// Kernel 0: clear the two amax slots (replaces hipMemsetAsync in the graph)
__global__ void init_kernel(unsigned* __restrict__ amax_bits) {
  if (threadIdx.x < 2) amax_bits[threadIdx.x] = 0u;
}

// ---------------------------------------------------------------------------
// Kernel 1: abs-max of A and V in one dispatch (blocks <2048 -> A, rest -> V)
__global__ void amax2_kernel(const float* __restrict__ a, long n4a,
                             const float* __restrict__ v, long n4v,
                             unsigned* __restrict__ out) {
  const f32x4* x4;
  long n4, i, stride;
  unsigned* dst;
  if (blockIdx.x < 2048) {
    x4 = (const f32x4*)a;  n4 = n4a;  dst = out;
    i = (long)blockIdx.x * blockDim.x + threadIdx.x;
    stride = 2048L * blockDim.x;
  } else {
    x4 = (const f32x4*)v;  n4 = n4v;  dst = out + 1;
    i = (long)(blockIdx.x - 2048) * blockDim.x + threadIdx.x;
    stride = 256L * blockDim.x;
  }
  float m = 0.0f;
  for (; i < n4; i += stride) {
    f32x4 val = x4[i];
    m = fmaxf(m, fmaxf(fmaxf(fabsf(val[0]), fabsf(val[1])),
                       fmaxf(fabsf(val[2]), fabsf(val[3]))));
  }
  #pragma unroll
  for (int off = 32; off; off >>= 1) m = fmaxf(m, __shfl_xor(m, off, 64));
  if ((threadIdx.x & 63) == 0) atomicMax(dst, __float_as_uint(m));
}

// ---------------------------------------------------------------------------
// HW e4m3fn quantization helpers (v_cvt_pk_fp8_f32 is RNE, OCP on gfx950).
__device__ __forceinline__ float clamp448(float y) {
  return fminf(fmaxf(y, -448.0f), 448.0f);
}

__device__ __forceinline__ unsigned pack_fp8x4(float a, float b, float c,
                                               float d) {
  int w = 0;
  w = __builtin_amdgcn_cvt_pk_fp8_f32(a, b, w, false);
  w = __builtin_amdgcn_cvt_pk_fp8_f32(c, d, w, true);
  return (unsigned)w;
}

__device__ __forceinline__ long pack_fp8x8(const float* f) {
  unsigned d0 = pack_fp8x4(f[0], f[1], f[2], f[3]);
  unsigned d1 = pack_fp8x4(f[4], f[5], f[6], f[7]);
  return (long)(((unsigned long long)d1 << 32) | d0);
}

// ---------------------------------------------------------------------------
// Kernel 2: quantize V -> Vq[bh][ks][d][j]  (j = s&31, fragment-major).
// Audit: ob byte (d*32 + sh*16 + q*4 + jj) = q(V[bh][ks*32 + sh*16+q*4+jj][d])
// i.e. Vq[bh][ks][d][k32] = q(V[bh][ks*32+k32][d]). A B-fragment for
// (ks, d in [ni*16,ni*16+16), k32 in [kg*8,kg*8+8)) is a dense 512-B block.
__global__ void quantv_tiled_kernel(const float* __restrict__ V,
                                    unsigned char* __restrict__ Vq,
                                    const unsigned* __restrict__ amax_bits) {
  float amax = fmaxf(__uint_as_float(amax_bits[1]), 1e-12f);
  float inv  = 448.0f / amax;
  int bh = blockIdx.x >> 6;          // grid = 32*64
  int ks = blockIdx.x & 63;
  const float*   vb = V  + ((size_t)bh * S_ + (size_t)ks * 32) * D_;
  unsigned char* ob = Vq + ((size_t)bh * NKS + ks) * VKS_B;
  int d  = threadIdx.x & 127;
  int sh = threadIdx.x >> 7;         // 0,1 (s-halves of 16)
  unsigned dw[4];
  #pragma unroll
  for (int q = 0; q < 4; ++q) {
    float f[4];
    #pragma unroll
    for (int j = 0; j < 4; ++j)
      f[j] = clamp448(vb[(size_t)(sh * 16 + q * 4 + j) * D_ + d] * inv);
    dw[q] = pack_fp8x4(f[0], f[1], f[2], f[3]);
  }
  *(uint4*)(ob + d * 32 + sh * 16) = *(const uint4*)dw;
}

// ---------------------------------------------------------------------------
// Kernel 3: fused quant+GEMM, per-lane only (no LDS, no barriers, no
// exchange). Structure = R2's proven gemm (A per-lane rows, in-register
// quant, same epilogue) with the two diagnosed defects fixed:
//  - B-fragments are dense 512-B wave loads from fragment-major Vq (L2)
//  - explicit 1-slab register double-buffer: ks+1's 2 A-loads + 8 B-loads
//    issue before ks's 8 MFMAs, so vmcnt never drains to cold.
__global__ __launch_bounds__(256, 4)
void gemm_fused_reg_kernel(const float* __restrict__ A,
                           const unsigned char* __restrict__ Vq,
                           float* __restrict__ out,
                           const unsigned* __restrict__ amax_bits) {
  float amax_a = fmaxf(__uint_as_float(amax_bits[0]), 1e-12f);
  float amax_v = fmaxf(__uint_as_float(amax_bits[1]), 1e-12f);
  float inv_a  = 448.0f / amax_a;
  float out_scale = (amax_a / 448.0f) * (amax_v / 448.0f);

  int bid = blockIdx.x;                      // 1024 blocks, 1024%8==0
  int swz = (bid & 7) * 128 + (bid >> 3);    // XCD-contiguous chunks (T1)
  int bh  = swz >> 5;
  int t0  = (swz & 31) * 64;

  int w    = threadIdx.x >> 6;               // wave 0..3 -> rows [t0+16w,+16)
  int lane = threadIdx.x & 63;
  int lr   = lane & 15;                      // A row-in-frag / B col / C col
  int kg   = lane >> 4;                      // k-group (k = kg*8 + j)

  const float* arow =
      A + (size_t)bh * T_ * S_ + (size_t)(t0 + w * 16 + lr) * S_ + kg * 8;
  const unsigned char* vbase =
      Vq + (size_t)bh * NKS * VKS_B + (size_t)lr * 32 + kg * 8;

  f32x4 acc[8];
  #pragma unroll
  for (int j = 0; j < 8; ++j) acc[j] = (f32x4)0.0f;

  // prologue: loads for ks=0
  f32x4 a0_cur = *(const f32x4*)(arow);
  f32x4 a1_cur = *(const f32x4*)(arow + 4);
  long  b_cur[8];
  #pragma unroll
  for (int ni = 0; ni < 8; ++ni)
    b_cur[ni] = *(const long*)(vbase + (size_t)ni * 512);

  for (int ks = 0; ks < NKS; ++ks) {
    // issue next slab's loads (clamped on last iter: redundant, harmless)
    int ksn = (ks + 1 < NKS) ? ks + 1 : ks;
    f32x4 a0_nxt = *(const f32x4*)(arow + (size_t)ksn * 32);
    f32x4 a1_nxt = *(const f32x4*)(arow + (size_t)ksn * 32 + 4);
    long  b_nxt[8];
    #pragma unroll
    for (int ni = 0; ni < 8; ++ni)
      b_nxt[ni] = *(const long*)(vbase + (size_t)ksn * VKS_B + ni * 512);

    // quantize current A fragment: bytes 0..7 = k = kg*8 + 0..7
    float f[8];
    #pragma unroll
    for (int j = 0; j < 4; ++j) {
      f[j]     = clamp448(a0_cur[j] * inv_a);
      f[j + 4] = clamp448(a1_cur[j] * inv_a);
    }
    long afrag = pack_fp8x8(f);

    #pragma unroll
    for (int ni = 0; ni < 8; ++ni)
      acc[ni] = __builtin_amdgcn_mfma_f32_16x16x32_fp8_fp8(afrag, b_cur[ni],
                                                           acc[ni], 0, 0, 0);

    a0_cur = a0_nxt;
    a1_cur = a1_nxt;
    #pragma unroll
    for (int ni = 0; ni < 8; ++ni) b_cur[ni] = b_nxt[ni];
  }

  // ---- epilogue: C/D layout col=lane&15, row=(lane>>4)*4+r  [guide §3, m89]
  // out[b][t][h][d], d = ni*16+lr, t = t0 + w*16 + kg*4 + r
  int b = bh >> 4, h = bh & 15;
  float* ob = out + (size_t)b * T_ * (H_ * D_) + (size_t)h * D_;
  int trow = t0 + w * 16;
  #pragma unroll
  for (int ni = 0; ni < 8; ++ni) {
    int d = ni * 16 + lr;
    #pragma unroll
    for (int r = 0; r < 4; ++r) {
      int t = trow + kg * 4 + r;
      ob[(size_t)t * (H_ * D_) + d] = acc[ni][r] * out_scale;
    }
  }
}

// ---------------------------------------------------------------------------
// Fallback (tiny d_ws): fused in-register quant GEMM, f32 A + f32 V direct.
__global__ __launch_bounds__(256, 4)
void gemm_fused_kernel(const float* __restrict__ A,
                       const float* __restrict__ Vf, float* __restrict__ out,
                       const unsigned* __restrict__ amax_bits) {
  float amax_a = fmaxf(__uint_as_float(amax_bits[0]), 1e-12f);
  float amax_v = fmaxf(__uint_as_float(amax_bits[1]), 1e-12f);
  float inv_a  = 448.0f / amax_a;
  float inv_v  = 448.0f / amax_v;
  float out_scale = (amax_a / 448.0f) * (amax_v / 448.0f);

  int bid  = blockIdx.x;
  int bh   = bid >> 5;
  int t0   = (bid & 31) * 64;
  int b    = bh >> 4;
  int h    = bh & 15;
  int wave = threadIdx.x >> 6;
  int lane = threadIdx.x & 63;
  int lr   = lane & 15;
  int kg   = lane >> 4;

  const float* arow =
      A + (size_t)bh * T_ * S_ + (size_t)(t0 + wave * 16 + lr) * S_;
  const float* vfb = Vf + (size_t)bh * S_ * D_;

  f32x4 acc[8];
  #pragma unroll
  for (int j = 0; j < 8; ++j) acc[j] = (f32x4)0.0f;

  for (int ks = 0; ks < S_ / 32; ++ks) {
    int kb = ks * 32 + kg * 8;
    long bfrag[8];
    #pragma unroll
    for (int ni = 0; ni < 8; ++ni) {
      float f[8];
      #pragma unroll
      for (int j = 0; j < 8; ++j)
        f[j] = clamp448(vfb[(size_t)(kb + j) * D_ + ni * 16 + lr] * inv_v);
      bfrag[ni] = pack_fp8x8(f);
    }
    f32x4 x0 = *(const f32x4*)(arow + kb);
    f32x4 x1 = *(const f32x4*)(arow + kb + 4);
    float f[8];
    #pragma unroll
    for (int j = 0; j < 4; ++j) {
      f[j]     = clamp448(x0[j] * inv_a);
      f[j + 4] = clamp448(x1[j] * inv_a);
    }
    long afrag = pack_fp8x8(f);
    #pragma unroll
    for (int ni = 0; ni < 8; ++ni)
      acc[ni] = __builtin_amdgcn_mfma_f32_16x16x32_fp8_fp8(afrag, bfrag[ni],
                                                           acc[ni], 0, 0, 0);
  }

  float* ob = out + (size_t)b * T_ * H_ * D_ + (size_t)h * D_;
  int trow = t0 + wave * 16;
  #pragma unroll
  for (int ni = 0; ni < 8; ++ni) {
    int d = ni * 16 + lr;
    #pragma unroll
    for (int r = 0; r < 4; ++r) {
      int t = trow + kg * 4 + r;
      ob[(size_t)t * H_ * D_ + d] = acc[ni][r] * out_scale;
    }
  }
}

// ---------------------------------------------------------------------------
extern "C" void kernel_launch(void* const* d_in, const int* in_sizes, int n_in,
                              void* d_out, int out_size, void* d_ws, size_t ws_size,
                              hipStream_t stream) {
  const float* aw = (const float*)d_in[0];
  const float* v  = (const float*)d_in[1];
  float* out      = (float*)d_out;

  unsigned*      amax_bits = (unsigned*)d_ws;
  unsigned char* vq        = (unsigned char*)d_ws + 256;
  size_t vq_bytes = (size_t)BH_ * NKS * VKS_B;            // 8 MB
  size_t need_full = 256 + vq_bytes;

  init_kernel<<<1, 64, 0, stream>>>(amax_bits);

  long n4a = (long)B_ * H_ * T_ * S_ / 4;
  long n4v = (long)B_ * H_ * S_ * D_ / 4;
  amax2_kernel<<<2304, 256, 0, stream>>>(aw, n4a, v, n4v, amax_bits);

  if (ws_size >= need_full) {
    quantv_tiled_kernel<<<BH_ * NKS, 256, 0, stream>>>(v, vq, amax_bits);
    gemm_fused_reg_kernel<<<BH_ * 32, 256, 0, stream>>>(aw, vq, out,
                                                        amax_bits);
  } else {
    gemm_fused_kernel<<<B_ * H_ * (T_ / 64), 256, 0, stream>>>(aw, v, out,
                                                               amax_bits);
  }
}

// Round 7
// 351.418 us; speedup vs baseline: 1.7098x; 1.0071x over previous
//
#include <hip/hip_runtime.h>
#include <stdint.h>

// Problem constants (from reference setup_inputs): B,H,T,S,D
#define B_ 2
#define H_ 16
#define T_ 2048
#define S_ 2048
#define D_ 128
#define BH_ (B_ * H_)              // 32
#define NKS (S_ / 32)              // 64 k-slots of 32 per bh
#define VKS_B (D_ * 32)            // 4 KB per (bh,ks) fp8 V tile

typedef float f32x4 __attribute__((ext_vector_type(4)));

// ---------------------------------------------------------------------------
// Kernel 0: clear the two amax slots (replaces hipMemsetAsync in the graph)
__global__ void init_kernel(unsigned* __restrict__ amax_bits) {
  if (threadIdx.x < 2) amax_bits[threadIdx.x] = 0u;
}

// ---------------------------------------------------------------------------
// Kernel 1: abs-max of A and V in one dispatch (blocks <2048 -> A, rest -> V)
__global__ void amax2_kernel(const float* __restrict__ a, long n4a,
                             const float* __restrict__ v, long n4v,
                             unsigned* __restrict__ out) {
  const f32x4* x4;
  long n4, i, stride;
  unsigned* dst;
  if (blockIdx.x < 2048) {
    x4 = (const f32x4*)a;  n4 = n4a;  dst = out;
    i = (long)blockIdx.x * blockDim.x + threadIdx.x;
    stride = 2048L * blockDim.x;
  } else {
    x4 = (const f32x4*)v;  n4 = n4v;  dst = out + 1;
    i = (long)(blockIdx.x - 2048) * blockDim.x + threadIdx.x;
    stride = 256L * blockDim.x;
  }
  float m = 0.0f;
  for (; i < n4; i += stride) {
    f32x4 val = x4[i];
    m = fmaxf(m, fmaxf(fmaxf(fabsf(val[0]), fabsf(val[1])),
                       fmaxf(fabsf(val[2]), fabsf(val[3]))));
  }
  #pragma unroll
  for (int off = 32; off; off >>= 1) m = fmaxf(m, __shfl_xor(m, off, 64));
  if ((threadIdx.x & 63) == 0) atomicMax(dst, __float_as_uint(m));
}

// ---------------------------------------------------------------------------
// HW e4m3fn quantization helpers (v_cvt_pk_fp8_f32 is RNE, OCP on gfx950).
__device__ __forceinline__ float clamp448(float y) {
  return fminf(fmaxf(y, -448.0f), 448.0f);
}

__device__ __forceinline__ unsigned pack_fp8x4(float a, float b, float c,
                                               float d) {
  int w = 0;
  w = __builtin_amdgcn_cvt_pk_fp8_f32(a, b, w, false);
  w = __builtin_amdgcn_cvt_pk_fp8_f32(c, d, w, true);
  return (unsigned)w;
}

__device__ __forceinline__ long pack_fp8x8(const float* f) {
  unsigned d0 = pack_fp8x4(f[0], f[1], f[2], f[3]);
  unsigned d1 = pack_fp8x4(f[4], f[5], f[6], f[7]);
  return (long)(((unsigned long long)d1 << 32) | d0);
}

// ---------------------------------------------------------------------------
// Kernel 2: quantize V -> Vq[bh][ks][d][j]  (j = s&31, fragment-major).
// Audit: ob byte (d*32 + sh*16 + q*4 + jj) = q(V[bh][ks*32 + sh*16+q*4+jj][d])
// i.e. Vq[bh][ks][d][k32] = q(V[bh][ks*32+k32][d]). A B-fragment for
// (ks, d in [ni*16,ni*16+16), k32 in [kg*8,kg*8+8)) is a dense 512-B block.
__global__ void quantv_tiled_kernel(const float* __restrict__ V,
                                    unsigned char* __restrict__ Vq,
                                    const unsigned* __restrict__ amax_bits) {
  float amax = fmaxf(__uint_as_float(amax_bits[1]), 1e-12f);
  float inv  = 448.0f / amax;
  int bh = blockIdx.x >> 6;          // grid = 32*64
  int ks = blockIdx.x & 63;
  const float*   vb = V  + ((size_t)bh * S_ + (size_t)ks * 32) * D_;
  unsigned char* ob = Vq + ((size_t)bh * NKS + ks) * VKS_B;
  int d  = threadIdx.x & 127;
  int sh = threadIdx.x >> 7;         // 0,1 (s-halves of 16)
  unsigned dw[4];
  #pragma unroll
  for (int q = 0; q < 4; ++q) {
    float f[4];
    #pragma unroll
    for (int j = 0; j < 4; ++j)
      f[j] = clamp448(vb[(size_t)(sh * 16 + q * 4 + j) * D_ + d] * inv);
    dw[q] = pack_fp8x4(f[0], f[1], f[2], f[3]);
  }
  *(uint4*)(ob + d * 32 + sh * 16) = *(const uint4*)dw;
}

// ---------------------------------------------------------------------------
// Kernel 3: fused quant+GEMM, per-lane only (no LDS, no barriers). R6
// structure with the loop-carried copies REMOVED: manual unroll-by-2
// ping-pong register sets (P0/P1), so there is no a_cur=a_nxt move for the
// compiler to rematerialize away (R2's VGPR=32 showed it sank the prefetch).
// Loads for ks+2 are issued right after ks is consumed -> ~1.5 half-bodies
// of latency coverage, x4 waves/SIMD.
__global__ __launch_bounds__(256, 4)
void gemm_fused_pp_kernel(const float* __restrict__ A,
                          const unsigned char* __restrict__ Vq,
                          float* __restrict__ out,
                          const unsigned* __restrict__ amax_bits) {
  float amax_a = fmaxf(__uint_as_float(amax_bits[0]), 1e-12f);
  float amax_v = fmaxf(__uint_as_float(amax_bits[1]), 1e-12f);
  float inv_a  = 448.0f / amax_a;
  float out_scale = (amax_a / 448.0f) * (amax_v / 448.0f);

  int bid = blockIdx.x;                      // 1024 blocks, 1024%8==0
  int swz = (bid & 7) * 128 + (bid >> 3);    // XCD-contiguous chunks (T1)
  int bh  = swz >> 5;
  int t0  = (swz & 31) * 64;

  int w    = threadIdx.x >> 6;               // wave 0..3 -> rows [t0+16w,+16)
  int lane = threadIdx.x & 63;
  int lr   = lane & 15;                      // A row-in-frag / B col / C col
  int kg   = lane >> 4;                      // k-group (k = kg*8 + j)

  const float* arow =
      A + (size_t)bh * T_ * S_ + (size_t)(t0 + w * 16 + lr) * S_ + kg * 8;
  const unsigned char* vbase =
      Vq + (size_t)bh * NKS * VKS_B + (size_t)lr * 32 + kg * 8;

  f32x4 acc[8];
  #pragma unroll
  for (int j = 0; j < 8; ++j) acc[j] = (f32x4)0.0f;

  // ping-pong sets
  f32x4 A0p0, A1p0, A0p1, A1p1;
  long  B0[8], B1[8];

  // prologue: ks=0 -> P0, ks=1 -> P1
  A0p0 = *(const f32x4*)(arow);
  A1p0 = *(const f32x4*)(arow + 4);
  #pragma unroll
  for (int ni = 0; ni < 8; ++ni)
    B0[ni] = *(const long*)(vbase + (size_t)ni * 512);
  A0p1 = *(const f32x4*)(arow + 32);
  A1p1 = *(const f32x4*)(arow + 36);
  #pragma unroll
  for (int ni = 0; ni < 8; ++ni)
    B1[ni] = *(const long*)(vbase + VKS_B + (size_t)ni * 512);

  #define QUANT_MFMA(A0r, A1r, Br)                                        \
    {                                                                     \
      float f[8];                                                         \
      _Pragma("unroll") for (int j = 0; j < 4; ++j) {                     \
        f[j]     = clamp448((A0r)[j] * inv_a);                            \
        f[j + 4] = clamp448((A1r)[j] * inv_a);                            \
      }                                                                   \
      long afrag = pack_fp8x8(f);                                         \
      _Pragma("unroll") for (int ni = 0; ni < 8; ++ni)                    \
        acc[ni] = __builtin_amdgcn_mfma_f32_16x16x32_fp8_fp8(             \
            afrag, (Br)[ni], acc[ni], 0, 0, 0);                           \
    }

  for (int ks = 0; ks < NKS - 2; ks += 2) {
    // consume P0 (= ks), refill with ks+2
    QUANT_MFMA(A0p0, A1p0, B0);
    A0p0 = *(const f32x4*)(arow + (size_t)(ks + 2) * 32);
    A1p0 = *(const f32x4*)(arow + (size_t)(ks + 2) * 32 + 4);
    #pragma unroll
    for (int ni = 0; ni < 8; ++ni)
      B0[ni] = *(const long*)(vbase + (size_t)(ks + 2) * VKS_B + ni * 512);
    // consume P1 (= ks+1), refill with ks+3
    QUANT_MFMA(A0p1, A1p1, B1);
    A0p1 = *(const f32x4*)(arow + (size_t)(ks + 3) * 32);
    A1p1 = *(const f32x4*)(arow + (size_t)(ks + 3) * 32 + 4);
    #pragma unroll
    for (int ni = 0; ni < 8; ++ni)
      B1[ni] = *(const long*)(vbase + (size_t)(ks + 3) * VKS_B + ni * 512);
  }
  // epilogue: ks = NKS-2, NKS-1 (already loaded, no refill)
  QUANT_MFMA(A0p0, A1p0, B0);
  QUANT_MFMA(A0p1, A1p1, B1);
  #undef QUANT_MFMA

  // ---- epilogue: C/D layout col=lane&15, row=(lane>>4)*4+r  [guide §3, m89]
  // out[b][t][h][d], d = ni*16+lr, t = t0 + w*16 + kg*4 + r
  int b = bh >> 4, h = bh & 15;
  float* ob = out + (size_t)b * T_ * (H_ * D_) + (size_t)h * D_;
  int trow = t0 + w * 16;
  #pragma unroll
  for (int ni = 0; ni < 8; ++ni) {
    int d = ni * 16 + lr;
    #pragma unroll
    for (int r = 0; r < 4; ++r) {
      int t = trow + kg * 4 + r;
      ob[(size_t)t * (H_ * D_) + d] = acc[ni][r] * out_scale;
    }
  }
}

// ---------------------------------------------------------------------------
// Fallback (tiny d_ws): fused in-register quant GEMM, f32 A + f32 V direct.
__global__ __launch_bounds__(256, 4)
void gemm_fused_kernel(const float* __restrict__ A,
                       const float* __restrict__ Vf, float* __restrict__ out,
                       const unsigned* __restrict__ amax_bits) {
  float amax_a = fmaxf(__uint_as_float(amax_bits[0]), 1e-12f);
  float amax_v = fmaxf(__uint_as_float(amax_bits[1]), 1e-12f);
  float inv_a  = 448.0f / amax_a;
  float inv_v  = 448.0f / amax_v;
  float out_scale = (amax_a / 448.0f) * (amax_v / 448.0f);

  int bid  = blockIdx.x;
  int bh   = bid >> 5;
  int t0   = (bid & 31) * 64;
  int b    = bh >> 4;
  int h    = bh & 15;
  int wave = threadIdx.x >> 6;
  int lane = threadIdx.x & 63;
  int lr   = lane & 15;
  int kg   = lane >> 4;

  const float* arow =
      A + (size_t)bh * T_ * S_ + (size_t)(t0 + wave * 16 + lr) * S_;
  const float* vfb = Vf + (size_t)bh * S_ * D_;

  f32x4 acc[8];
  #pragma unroll
  for (int j = 0; j < 8; ++j) acc[j] = (f32x4)0.0f;

  for (int ks = 0; ks < S_ / 32; ++ks) {
    int kb = ks * 32 + kg * 8;
    long bfrag[8];
    #pragma unroll
    for (int ni = 0; ni < 8; ++ni) {
      float f[8];
      #pragma unroll
      for (int j = 0; j < 8; ++j)
        f[j] = clamp448(vfb[(size_t)(kb + j) * D_ + ni * 16 + lr] * inv_v);
      bfrag[ni] = pack_fp8x8(f);
    }
    f32x4 x0 = *(const f32x4*)(arow + kb);
    f32x4 x1 = *(const f32x4*)(arow + kb + 4);
    float f[8];
    #pragma unroll
    for (int j = 0; j < 4; ++j) {
      f[j]     = clamp448(x0[j] * inv_a);
      f[j + 4] = clamp448(x1[j] * inv_a);
    }
    long afrag = pack_fp8x8(f);
    #pragma unroll
    for (int ni = 0; ni < 8; ++ni)
      acc[ni] = __builtin_amdgcn_mfma_f32_16x16x32_fp8_fp8(afrag, bfrag[ni],
                                                           acc[ni], 0, 0, 0);
  }

  float* ob = out + (size_t)b * T_ * H_ * D_ + (size_t)h * D_;
  int trow = t0 + wave * 16;
  #pragma unroll
  for (int ni = 0; ni < 8; ++ni) {
    int d = ni * 16 + lr;
    #pragma unroll
    for (int r = 0; r < 4; ++r) {
      int t = trow + kg * 4 + r;
      ob[(size_t)t * H_ * D_ + d] = acc[ni][r] * out_scale;
    }
  }
}

// ---------------------------------------------------------------------------
extern "C" void kernel_launch(void* const* d_in, const int* in_sizes, int n_in,
                              void* d_out, int out_size, void* d_ws, size_t ws_size,
                              hipStream_t stream) {
  const float* aw = (const float*)d_in[0];
  const float* v  = (const float*)d_in[1];
  float* out      = (float*)d_out;

  unsigned*      amax_bits = (unsigned*)d_ws;
  unsigned char* vq        = (unsigned char*)d_ws + 256;
  size_t vq_bytes = (size_t)BH_ * NKS * VKS_B;            // 8 MB
  size_t need_full = 256 + vq_bytes;

  init_kernel<<<1, 64, 0, stream>>>(amax_bits);

  long n4a = (long)B_ * H_ * T_ * S_ / 4;
  long n4v = (long)B_ * H_ * S_ * D_ / 4;
  amax2_kernel<<<2304, 256, 0, stream>>>(aw, n4a, v, n4v, amax_bits);

  if (ws_size >= need_full) {
    quantv_tiled_kernel<<<BH_ * NKS, 256, 0, stream>>>(v, vq, amax_bits);
    gemm_fused_pp_kernel<<<BH_ * 32, 256, 0, stream>>>(aw, vq, out,
                                                       amax_bits);
  } else {
    gemm_fused_kernel<<<B_ * H_ * (T_ / 64), 256, 0, stream>>>(aw, v, out,
                                                               amax_bits);
  }
}

// Round 8
// 345.406 us; speedup vs baseline: 1.7396x; 1.0174x over previous
//
#include <hip/hip_runtime.h>
#include <stdint.h>

// Problem constants (from reference setup_inputs): B,H,T,S,D
#define B_ 2
#define H_ 16
#define T_ 2048
#define S_ 2048
#define D_ 128
#define BH_ (B_ * H_)              // 32
#define NKS (S_ / 32)              // 64 k-slots of 32 per bh
#define VKS_B (D_ * 32)            // 4 KB per (bh,ks) fp8 V tile

typedef float f32x4 __attribute__((ext_vector_type(4)));

// ---------------------------------------------------------------------------
// Kernel 0: clear the two amax slots (replaces hipMemsetAsync in the graph)
__global__ void init_kernel(unsigned* __restrict__ amax_bits) {
  if (threadIdx.x < 2) amax_bits[threadIdx.x] = 0u;
}

// ---------------------------------------------------------------------------
// Kernel 1: abs-max of A and V in one dispatch (blocks <2048 -> A, rest -> V)
__global__ void amax2_kernel(const float* __restrict__ a, long n4a,
                             const float* __restrict__ v, long n4v,
                             unsigned* __restrict__ out) {
  const f32x4* x4;
  long n4, i, stride;
  unsigned* dst;
  if (blockIdx.x < 2048) {
    x4 = (const f32x4*)a;  n4 = n4a;  dst = out;
    i = (long)blockIdx.x * blockDim.x + threadIdx.x;
    stride = 2048L * blockDim.x;
  } else {
    x4 = (const f32x4*)v;  n4 = n4v;  dst = out + 1;
    i = (long)(blockIdx.x - 2048) * blockDim.x + threadIdx.x;
    stride = 256L * blockDim.x;
  }
  float m = 0.0f;
  for (; i < n4; i += stride) {
    f32x4 val = x4[i];
    m = fmaxf(m, fmaxf(fmaxf(fabsf(val[0]), fabsf(val[1])),
                       fmaxf(fabsf(val[2]), fabsf(val[3]))));
  }
  #pragma unroll
  for (int off = 32; off; off >>= 1) m = fmaxf(m, __shfl_xor(m, off, 64));
  if ((threadIdx.x & 63) == 0) atomicMax(dst, __float_as_uint(m));
}

// ---------------------------------------------------------------------------
// HW e4m3fn quantization helpers (v_cvt_pk_fp8_f32 is RNE, OCP on gfx950).
__device__ __forceinline__ float clamp448(float y) {
  return fminf(fmaxf(y, -448.0f), 448.0f);
}

__device__ __forceinline__ unsigned pack_fp8x4(float a, float b, float c,
                                               float d) {
  int w = 0;
  w = __builtin_amdgcn_cvt_pk_fp8_f32(a, b, w, false);
  w = __builtin_amdgcn_cvt_pk_fp8_f32(c, d, w, true);
  return (unsigned)w;
}

__device__ __forceinline__ long pack_fp8x8(const float* f) {
  unsigned d0 = pack_fp8x4(f[0], f[1], f[2], f[3]);
  unsigned d1 = pack_fp8x4(f[4], f[5], f[6], f[7]);
  return (long)(((unsigned long long)d1 << 32) | d0);
}

__device__ __forceinline__ long mk64(unsigned lo, unsigned hi) {
  return (long)(((unsigned long long)hi << 32) | lo);
}

// ---------------------------------------------------------------------------
// Kernel 2: quantize V -> Vq[bh][ks][lane][64B], per-lane CONTIGUOUS B data:
//   byte (lane, ni*8 + j) = q( V[bh][ks*32 + (lane>>4)*8 + j][ni*16 + (lane&15)] )
// so in the GEMM, lane (kg=lane>>4, lr=lane&15) loads its 8 B-fragments
// (ni=0..7) as FOUR dwordx4 loads; the wave's access is a dense 4-KB block.
// Same (d,k)->lane bytes as the R7-passing layout, just repacked.
__global__ void quantv_lane_kernel(const float* __restrict__ V,
                                   unsigned char* __restrict__ Vq,
                                   const unsigned* __restrict__ amax_bits) {
  float amax = fmaxf(__uint_as_float(amax_bits[1]), 1e-12f);
  float inv  = 448.0f / amax;
  int bh = blockIdx.x >> 6;          // grid = 32*64
  int ks = blockIdx.x & 63;
  const float*   vb = V  + ((size_t)bh * S_ + (size_t)ks * 32) * D_;
  unsigned char* ob = Vq + ((size_t)bh * NKS + ks) * VKS_B;
  int lane = threadIdx.x & 63;
  int p    = threadIdx.x >> 6;       // 0..3 -> fragments ni = 2p, 2p+1
  int kg   = lane >> 4;
  int lr   = lane & 15;
  unsigned dw[4];
  #pragma unroll
  for (int q = 0; q < 2; ++q) {      // ni = 2p + q
    int d = (2 * p + q) * 16 + lr;
    float f[8];
    #pragma unroll
    for (int j = 0; j < 8; ++j)
      f[j] = clamp448(vb[(size_t)(kg * 8 + j) * D_ + d] * inv);
    dw[q * 2 + 0] = pack_fp8x4(f[0], f[1], f[2], f[3]);
    dw[q * 2 + 1] = pack_fp8x4(f[4], f[5], f[6], f[7]);
  }
  *(uint4*)(ob + lane * 64 + p * 16) = *(const uint4*)dw;
}

// ---------------------------------------------------------------------------
// Kernel 3: fused quant+GEMM, per-lane only (no LDS, no barriers).
// R7 ping-pong structure, two changes aimed at the diagnosed register
// starvation (R2: VGPR_Count=32 -> compiler serialized every load):
//  1. __launch_bounds__(256, 1): free the register allocator so the
//     ping-pong buffers actually live in registers (grid keeps 4 blk/CU).
//  2. B via 4x dwordx4/ks from the lane-contiguous Vq (6 VMEM/ks, was 10).
__global__ __launch_bounds__(256, 1)
void gemm_fused_pp_kernel(const float* __restrict__ A,
                          const unsigned char* __restrict__ Vq,
                          float* __restrict__ out,
                          const unsigned* __restrict__ amax_bits) {
  float amax_a = fmaxf(__uint_as_float(amax_bits[0]), 1e-12f);
  float amax_v = fmaxf(__uint_as_float(amax_bits[1]), 1e-12f);
  float inv_a  = 448.0f / amax_a;
  float out_scale = (amax_a / 448.0f) * (amax_v / 448.0f);

  int bid = blockIdx.x;                      // 1024 blocks, 1024%8==0
  int swz = (bid & 7) * 128 + (bid >> 3);    // XCD-contiguous chunks (T1)
  int bh  = swz >> 5;
  int t0  = (swz & 31) * 64;

  int w    = threadIdx.x >> 6;               // wave 0..3 -> rows [t0+16w,+16)
  int lane = threadIdx.x & 63;
  int lr   = lane & 15;                      // A row-in-frag / B col / C col
  int kg   = lane >> 4;                      // k-group (k = kg*8 + j)

  const float* arow =
      A + (size_t)bh * T_ * S_ + (size_t)(t0 + w * 16 + lr) * S_ + kg * 8;
  const unsigned char* vlane =
      Vq + (size_t)bh * NKS * VKS_B + (size_t)lane * 64;

  f32x4 acc[8];
  #pragma unroll
  for (int j = 0; j < 8; ++j) acc[j] = (f32x4)0.0f;

  // ping-pong sets
  f32x4 A0p0, A1p0, A0p1, A1p1;
  uint4 B0[4], B1[4];

  // prologue: ks=0 -> P0, ks=1 -> P1
  A0p0 = *(const f32x4*)(arow);
  A1p0 = *(const f32x4*)(arow + 4);
  #pragma unroll
  for (int i = 0; i < 4; ++i)
    B0[i] = *(const uint4*)(vlane + i * 16);
  A0p1 = *(const f32x4*)(arow + 32);
  A1p1 = *(const f32x4*)(arow + 36);
  #pragma unroll
  for (int i = 0; i < 4; ++i)
    B1[i] = *(const uint4*)(vlane + VKS_B + i * 16);

  #define QUANT_MFMA(A0r, A1r, Br)                                        \
    {                                                                     \
      float f[8];                                                         \
      _Pragma("unroll") for (int j = 0; j < 4; ++j) {                     \
        f[j]     = clamp448((A0r)[j] * inv_a);                            \
        f[j + 4] = clamp448((A1r)[j] * inv_a);                            \
      }                                                                   \
      long afrag = pack_fp8x8(f);                                         \
      _Pragma("unroll") for (int i = 0; i < 4; ++i) {                     \
        acc[2 * i] = __builtin_amdgcn_mfma_f32_16x16x32_fp8_fp8(          \
            afrag, mk64((Br)[i].x, (Br)[i].y), acc[2 * i], 0, 0, 0);      \
        acc[2 * i + 1] = __builtin_amdgcn_mfma_f32_16x16x32_fp8_fp8(      \
            afrag, mk64((Br)[i].z, (Br)[i].w), acc[2 * i + 1], 0, 0, 0);  \
      }                                                                   \
    }

  for (int ks = 0; ks < NKS - 2; ks += 2) {
    // consume P0 (= ks), refill with ks+2
    QUANT_MFMA(A0p0, A1p0, B0);
    A0p0 = *(const f32x4*)(arow + (size_t)(ks + 2) * 32);
    A1p0 = *(const f32x4*)(arow + (size_t)(ks + 2) * 32 + 4);
    #pragma unroll
    for (int i = 0; i < 4; ++i)
      B0[i] = *(const uint4*)(vlane + (size_t)(ks + 2) * VKS_B + i * 16);
    // consume P1 (= ks+1), refill with ks+3
    QUANT_MFMA(A0p1, A1p1, B1);
    A0p1 = *(const f32x4*)(arow + (size_t)(ks + 3) * 32);
    A1p1 = *(const f32x4*)(arow + (size_t)(ks + 3) * 32 + 4);
    #pragma unroll
    for (int i = 0; i < 4; ++i)
      B1[i] = *(const uint4*)(vlane + (size_t)(ks + 3) * VKS_B + i * 16);
  }
  // epilogue: ks = NKS-2, NKS-1 (already loaded, no refill)
  QUANT_MFMA(A0p0, A1p0, B0);
  QUANT_MFMA(A0p1, A1p1, B1);
  #undef QUANT_MFMA

  // ---- epilogue: C/D layout col=lane&15, row=(lane>>4)*4+r  [guide §3, m89]
  // out[b][t][h][d], d = ni*16+lr, t = t0 + w*16 + kg*4 + r
  int b = bh >> 4, h = bh & 15;
  float* ob = out + (size_t)b * T_ * (H_ * D_) + (size_t)h * D_;
  int trow = t0 + w * 16;
  #pragma unroll
  for (int ni = 0; ni < 8; ++ni) {
    int d = ni * 16 + lr;
    #pragma unroll
    for (int r = 0; r < 4; ++r) {
      int t = trow + kg * 4 + r;
      ob[(size_t)t * (H_ * D_) + d] = acc[ni][r] * out_scale;
    }
  }
}

// ---------------------------------------------------------------------------
// Fallback (tiny d_ws): fused in-register quant GEMM, f32 A + f32 V direct.
__global__ __launch_bounds__(256, 4)
void gemm_fused_kernel(const float* __restrict__ A,
                       const float* __restrict__ Vf, float* __restrict__ out,
                       const unsigned* __restrict__ amax_bits) {
  float amax_a = fmaxf(__uint_as_float(amax_bits[0]), 1e-12f);
  float amax_v = fmaxf(__uint_as_float(amax_bits[1]), 1e-12f);
  float inv_a  = 448.0f / amax_a;
  float inv_v  = 448.0f / amax_v;
  float out_scale = (amax_a / 448.0f) * (amax_v / 448.0f);

  int bid  = blockIdx.x;
  int bh   = bid >> 5;
  int t0   = (bid & 31) * 64;
  int b    = bh >> 4;
  int h    = bh & 15;
  int wave = threadIdx.x >> 6;
  int lane = threadIdx.x & 63;
  int lr   = lane & 15;
  int kg   = lane >> 4;

  const float* arow =
      A + (size_t)bh * T_ * S_ + (size_t)(t0 + wave * 16 + lr) * S_;
  const float* vfb = Vf + (size_t)bh * S_ * D_;

  f32x4 acc[8];
  #pragma unroll
  for (int j = 0; j < 8; ++j) acc[j] = (f32x4)0.0f;

  for (int ks = 0; ks < S_ / 32; ++ks) {
    int kb = ks * 32 + kg * 8;
    long bfrag[8];
    #pragma unroll
    for (int ni = 0; ni < 8; ++ni) {
      float f[8];
      #pragma unroll
      for (int j = 0; j < 8; ++j)
        f[j] = clamp448(vfb[(size_t)(kb + j) * D_ + ni * 16 + lr] * inv_v);
      bfrag[ni] = pack_fp8x8(f);
    }
    f32x4 x0 = *(const f32x4*)(arow + kb);
    f32x4 x1 = *(const f32x4*)(arow + kb + 4);
    float f[8];
    #pragma unroll
    for (int j = 0; j < 4; ++j) {
      f[j]     = clamp448(x0[j] * inv_a);
      f[j + 4] = clamp448(x1[j] * inv_a);
    }
    long afrag = pack_fp8x8(f);
    #pragma unroll
    for (int ni = 0; ni < 8; ++ni)
      acc[ni] = __builtin_amdgcn_mfma_f32_16x16x32_fp8_fp8(afrag, bfrag[ni],
                                                           acc[ni], 0, 0, 0);
  }

  float* ob = out + (size_t)b * T_ * H_ * D_ + (size_t)h * D_;
  int trow = t0 + wave * 16;
  #pragma unroll
  for (int ni = 0; ni < 8; ++ni) {
    int d = ni * 16 + lr;
    #pragma unroll
    for (int r = 0; r < 4; ++r) {
      int t = trow + kg * 4 + r;
      ob[(size_t)t * H_ * D_ + d] = acc[ni][r] * out_scale;
    }
  }
}

// ---------------------------------------------------------------------------
extern "C" void kernel_launch(void* const* d_in, const int* in_sizes, int n_in,
                              void* d_out, int out_size, void* d_ws, size_t ws_size,
                              hipStream_t stream) {
  const float* aw = (const float*)d_in[0];
  const float* v  = (const float*)d_in[1];
  float* out      = (float*)d_out;

  unsigned*      amax_bits = (unsigned*)d_ws;
  unsigned char* vq        = (unsigned char*)d_ws + 256;
  size_t vq_bytes = (size_t)BH_ * NKS * VKS_B;            // 8 MB
  size_t need_full = 256 + vq_bytes;

  init_kernel<<<1, 64, 0, stream>>>(amax_bits);

  long n4a = (long)B_ * H_ * T_ * S_ / 4;
  long n4v = (long)B_ * H_ * S_ * D_ / 4;
  amax2_kernel<<<2304, 256, 0, stream>>>(aw, n4a, v, n4v, amax_bits);

  if (ws_size >= need_full) {
    quantv_lane_kernel<<<BH_ * NKS, 256, 0, stream>>>(v, vq, amax_bits);
    gemm_fused_pp_kernel<<<BH_ * 32, 256, 0, stream>>>(aw, vq, out,
                                                       amax_bits);
  } else {
    gemm_fused_kernel<<<B_ * H_ * (T_ / 64), 256, 0, stream>>>(aw, v, out,
                                                               amax_bits);
  }
}

// Round 9
// 340.205 us; speedup vs baseline: 1.7662x; 1.0153x over previous
//
#include <hip/hip_runtime.h>
#include <stdint.h>

// Problem constants (from reference setup_inputs): B,H,T,S,D
#define B_ 2
#define H_ 16
#define T_ 2048
#define S_ 2048
#define D_ 128
#define BH_ (B_ * H_)              // 32
#define NKS (S_ / 32)              // 64 k-slots of 32 per bh
#define VKS_B 4096                 // 4 KB per (bh,ks) fp8 V tile
#define NSLAB 32                   // slabs of BK=64 floats (2 k-slots each)

typedef float f32x4 __attribute__((ext_vector_type(4)));

// ---------------------------------------------------------------------------
// Kernel 0: clear the two amax slots (replaces hipMemsetAsync in the graph)
__global__ void init_kernel(unsigned* __restrict__ amax_bits) {
  if (threadIdx.x < 2) amax_bits[threadIdx.x] = 0u;
}

// ---------------------------------------------------------------------------
// Kernel 1: abs-max of A and V in one dispatch (blocks <2048 -> A, rest -> V)
__global__ void amax2_kernel(const float* __restrict__ a, long n4a,
                             const float* __restrict__ v, long n4v,
                             unsigned* __restrict__ out) {
  const f32x4* x4;
  long n4, i, stride;
  unsigned* dst;
  if (blockIdx.x < 2048) {
    x4 = (const f32x4*)a;  n4 = n4a;  dst = out;
    i = (long)blockIdx.x * blockDim.x + threadIdx.x;
    stride = 2048L * blockDim.x;
  } else {
    x4 = (const f32x4*)v;  n4 = n4v;  dst = out + 1;
    i = (long)(blockIdx.x - 2048) * blockDim.x + threadIdx.x;
    stride = 256L * blockDim.x;
  }
  float m = 0.0f;
  for (; i < n4; i += stride) {
    f32x4 val = x4[i];
    m = fmaxf(m, fmaxf(fmaxf(fabsf(val[0]), fabsf(val[1])),
                       fmaxf(fabsf(val[2]), fabsf(val[3]))));
  }
  #pragma unroll
  for (int off = 32; off; off >>= 1) m = fmaxf(m, __shfl_xor(m, off, 64));
  if ((threadIdx.x & 63) == 0) atomicMax(dst, __float_as_uint(m));
}

// ---------------------------------------------------------------------------
// HW e4m3fn quantization helpers (v_cvt_pk_fp8_f32 is RNE, OCP on gfx950).
__device__ __forceinline__ float clamp448(float y) {
  return fminf(fmaxf(y, -448.0f), 448.0f);
}

__device__ __forceinline__ unsigned pack_fp8x4(float a, float b, float c,
                                               float d) {
  int w = 0;
  w = __builtin_amdgcn_cvt_pk_fp8_f32(a, b, w, false);
  w = __builtin_amdgcn_cvt_pk_fp8_f32(c, d, w, true);
  return (unsigned)w;
}

__device__ __forceinline__ long pack_fp8x8(const float* f) {
  unsigned d0 = pack_fp8x4(f[0], f[1], f[2], f[3]);
  unsigned d1 = pack_fp8x4(f[4], f[5], f[6], f[7]);
  return (long)(((unsigned long long)d1 << 32) | d0);
}

__device__ __forceinline__ long mk64(unsigned lo, unsigned hi) {
  return (long)(((unsigned long long)hi << 32) | lo);
}

// async global->LDS, 16B/lane; lptr is the WAVE-UNIFORM base (HW adds
// lane*16), gptr is per-lane [guide §5, m97/m104].
__device__ __forceinline__ void gload_lds16(const void* g, void* l) {
  __builtin_amdgcn_global_load_lds(
      (const __attribute__((address_space(1))) unsigned int*)g,
      (__attribute__((address_space(3))) unsigned int*)l, 16, 0, 0);
}

// ---------------------------------------------------------------------------
// Kernel 2: quantize V -> Vq[bh][ks][i][lane][16B]  (i-major so it matches the
// GEMM's B-LDS layout byte-for-byte; staging is then a linear copy).
// Content per (lane,i): fragments ni=2i,2i+1 for (kg=lane>>4, lr=lane&15):
//   byte j of half q = q8( V[bh][ks*32 + kg*8 + j][ (2i+q)*16 + lr ] )
// Same bytes as the R7/R8-passing layouts, repacked.
__global__ void quantv_ldsorder_kernel(const float* __restrict__ V,
                                       unsigned char* __restrict__ Vq,
                                       const unsigned* __restrict__ amax_bits) {
  float amax = fmaxf(__uint_as_float(amax_bits[1]), 1e-12f);
  float inv  = 448.0f / amax;
  int bh = blockIdx.x >> 6;          // grid = 32*64
  int ks = blockIdx.x & 63;
  const float*   vb = V  + ((size_t)bh * S_ + (size_t)ks * 32) * D_;
  unsigned char* ob = Vq + ((size_t)bh * NKS + ks) * VKS_B;
  int lane = threadIdx.x & 63;
  int p    = threadIdx.x >> 6;       // 0..3 = i (also the wave id)
  int kg   = lane >> 4;
  int lr   = lane & 15;
  unsigned dw[4];
  #pragma unroll
  for (int q = 0; q < 2; ++q) {      // ni = 2p + q
    int d = (2 * p + q) * 16 + lr;
    float f[8];
    #pragma unroll
    for (int j = 0; j < 8; ++j)
      f[j] = clamp448(vb[(size_t)(kg * 8 + j) * D_ + d] * inv);
    dw[q * 2 + 0] = pack_fp8x4(f[0], f[1], f[2], f[3]);
    dw[q * 2 + 1] = pack_fp8x4(f[4], f[5], f[6], f[7]);
  }
  *(uint4*)(ob + p * 1024 + lane * 16) = *(const uint4*)dw;   // wave-dense 1KB
}

// ---------------------------------------------------------------------------
// Kernel 3: fused quant+GEMM, m97/m230-style 2-phase global_load_lds
// template (proven 682-874 TF on this chip; we need ~350).
//  - block = 4 waves, 64x128 C-tile; wave owns 16 rows.
//  - per slab (BK=64 floats): stage A 16KB (f32, XOR-pre-swizzled source,
//    linear LDS dest) + B 8KB (linear copy of Vq tile) via global_load_lds;
//    one __syncthreads per slab (compiler drains vmcnt there).
//  - compute: 2 k-steps x { 2x ds_read_b128 A (swizzled, conflict-free),
//    quant via HW cvt_pk, 4x ds_read_b128 B, 16 MFMA fp8 }.
//  - LDS 48KB -> 3 blocks/CU: cross-block overlap absorbs the barrier drain.
__global__ __launch_bounds__(256, 3)
void gemm_lds_kernel(const float* __restrict__ A,
                     const unsigned char* __restrict__ Vq,
                     float* __restrict__ out,
                     const unsigned* __restrict__ amax_bits) {
  __shared__ __align__(16) unsigned char sA[2][16384];   // [buf][row][256B]
  __shared__ __align__(16) unsigned char sB[2][8192];    // [buf][ks][i][l][16]

  float amax_a = fmaxf(__uint_as_float(amax_bits[0]), 1e-12f);
  float amax_v = fmaxf(__uint_as_float(amax_bits[1]), 1e-12f);
  float inv_a  = 448.0f / amax_a;
  float out_scale = (amax_a / 448.0f) * (amax_v / 448.0f);

  int bid = blockIdx.x;                      // 1024 blocks, 1024%8==0
  int swz = (bid & 7) * 128 + (bid >> 3);    // XCD-contiguous chunks (T1)
  int bh  = swz >> 5;
  int t0  = (swz & 31) * 64;

  int w    = threadIdx.x >> 6;               // wave 0..3 -> rows [t0+16w,+16)
  int lane = threadIdx.x & 63;
  int lr   = lane & 15;                      // A row-in-frag / B col / C col
  int kg   = lane >> 4;                      // k-group (k = kg*8 + j)
  int swzA = (lr & 7) << 4;                  // read-side XOR (lane-constant)

  const char* abase = (const char*)A + (size_t)bh * T_ * S_ * 4;
  const unsigned char* vpanel = Vq + (size_t)bh * NKS * VKS_B;

  f32x4 acc[8];
  #pragma unroll
  for (int j = 0; j < 8; ++j) acc[j] = (f32x4)0.0f;

  // ---- staging helpers (each wave stages its own 16 A rows + 2KB of B) ----
  auto stageA = [&](int buf, int s) {
    #pragma unroll
    for (int i = 0; i < 4; ++i) {
      int row_local = i * 4 + (lane >> 4);             // 0..15
      int grow = t0 + w * 16 + row_local;
      // source pre-swizzled so linear LDS holds A[row][col ^ ((row&7)<<4)]
      const char* src = abase + ((size_t)grow * S_ + (size_t)s * 64) * 4 +
                        (((lane & 15) * 16) ^ ((row_local & 7) << 4));
      gload_lds16(src, &sA[buf][w * 4096 + i * 1024]);
    }
  };
  auto stageB = [&](int buf, int s) {
    const unsigned char* vt = vpanel + (size_t)(s * 2) * VKS_B;
    #pragma unroll
    for (int j = 0; j < 2; ++j)
      gload_lds16(vt + w * 2048 + j * 1024 + lane * 16,
                  &sB[buf][w * 2048 + j * 1024]);
  };
  auto compute = [&](int buf) {
    #pragma unroll
    for (int ks = 0; ks < 2; ++ks) {
      const unsigned char* ab = &sA[buf][w * 4096 + lr * 256];
      f32x4 x0 = *(const f32x4*)(ab + ((ks * 128 + kg * 32) ^ swzA));
      f32x4 x1 = *(const f32x4*)(ab + ((ks * 128 + kg * 32 + 16) ^ swzA));
      float f[8];
      #pragma unroll
      for (int j = 0; j < 4; ++j) {
        f[j]     = clamp448(x0[j] * inv_a);
        f[j + 4] = clamp448(x1[j] * inv_a);
      }
      long afrag = pack_fp8x8(f);
      const unsigned char* bb = &sB[buf][ks * 4096 + lane * 16];
      #pragma unroll
      for (int i = 0; i < 4; ++i) {
        uint4 bv = *(const uint4*)(bb + i * 1024);
        acc[2 * i] = __builtin_amdgcn_mfma_f32_16x16x32_fp8_fp8(
            afrag, mk64(bv.x, bv.y), acc[2 * i], 0, 0, 0);
        acc[2 * i + 1] = __builtin_amdgcn_mfma_f32_16x16x32_fp8_fp8(
            afrag, mk64(bv.z, bv.w), acc[2 * i + 1], 0, 0, 0);
      }
    }
  };

  // ---- 2-phase pipeline: STAGE(next); compute(cur); sync  [guide §5.5 T3]
  stageA(0, 0);
  stageB(0, 0);
  __syncthreads();
  int buf = 0;
  for (int t = 0; t < NSLAB; ++t) {
    if (t + 1 < NSLAB) {
      stageA(buf ^ 1, t + 1);
      stageB(buf ^ 1, t + 1);
    }
    compute(buf);
    __syncthreads();
    buf ^= 1;
  }

  // ---- epilogue: C/D layout col=lane&15, row=(lane>>4)*4+r  [guide §3, m89]
  // out[b][t][h][d], d = ni*16+lr, t = t0 + w*16 + kg*4 + r
  int b = bh >> 4, h = bh & 15;
  float* ob = out + (size_t)b * T_ * (H_ * D_) + (size_t)h * D_;
  int trow = t0 + w * 16;
  #pragma unroll
  for (int ni = 0; ni < 8; ++ni) {
    int d = ni * 16 + lr;
    #pragma unroll
    for (int r = 0; r < 4; ++r) {
      int t = trow + kg * 4 + r;
      ob[(size_t)t * (H_ * D_) + d] = acc[ni][r] * out_scale;
    }
  }
}

// ---------------------------------------------------------------------------
// Fallback (tiny d_ws): fused in-register quant GEMM, f32 A + f32 V direct.
__global__ __launch_bounds__(256, 4)
void gemm_fused_kernel(const float* __restrict__ A,
                       const float* __restrict__ Vf, float* __restrict__ out,
                       const unsigned* __restrict__ amax_bits) {
  float amax_a = fmaxf(__uint_as_float(amax_bits[0]), 1e-12f);
  float amax_v = fmaxf(__uint_as_float(amax_bits[1]), 1e-12f);
  float inv_a  = 448.0f / amax_a;
  float inv_v  = 448.0f / amax_v;
  float out_scale = (amax_a / 448.0f) * (amax_v / 448.0f);

  int bid  = blockIdx.x;
  int bh   = bid >> 5;
  int t0   = (bid & 31) * 64;
  int b    = bh >> 4;
  int h    = bh & 15;
  int wave = threadIdx.x >> 6;
  int lane = threadIdx.x & 63;
  int lr   = lane & 15;
  int kg   = lane >> 4;

  const float* arow =
      A + (size_t)bh * T_ * S_ + (size_t)(t0 + wave * 16 + lr) * S_;
  const float* vfb = Vf + (size_t)bh * S_ * D_;

  f32x4 acc[8];
  #pragma unroll
  for (int j = 0; j < 8; ++j) acc[j] = (f32x4)0.0f;

  for (int ks = 0; ks < S_ / 32; ++ks) {
    int kb = ks * 32 + kg * 8;
    long bfrag[8];
    #pragma unroll
    for (int ni = 0; ni < 8; ++ni) {
      float f[8];
      #pragma unroll
      for (int j = 0; j < 8; ++j)
        f[j] = clamp448(vfb[(size_t)(kb + j) * D_ + ni * 16 + lr] * inv_v);
      bfrag[ni] = pack_fp8x8(f);
    }
    f32x4 x0 = *(const f32x4*)(arow + kb);
    f32x4 x1 = *(const f32x4*)(arow + kb + 4);
    float f[8];
    #pragma unroll
    for (int j = 0; j < 4; ++j) {
      f[j]     = clamp448(x0[j] * inv_a);
      f[j + 4] = clamp448(x1[j] * inv_a);
    }
    long afrag = pack_fp8x8(f);
    #pragma unroll
    for (int ni = 0; ni < 8; ++ni)
      acc[ni] = __builtin_amdgcn_mfma_f32_16x16x32_fp8_fp8(afrag, bfrag[ni],
                                                           acc[ni], 0, 0, 0);
  }

  float* ob = out + (size_t)b * T_ * H_ * D_ + (size_t)h * D_;
  int trow = t0 + wave * 16;
  #pragma unroll
  for (int ni = 0; ni < 8; ++ni) {
    int d = ni * 16 + lr;
    #pragma unroll
    for (int r = 0; r < 4; ++r) {
      int t = trow + kg * 4 + r;
      ob[(size_t)t * H_ * D_ + d] = acc[ni][r] * out_scale;
    }
  }
}

// ---------------------------------------------------------------------------
extern "C" void kernel_launch(void* const* d_in, const int* in_sizes, int n_in,
                              void* d_out, int out_size, void* d_ws, size_t ws_size,
                              hipStream_t stream) {
  const float* aw = (const float*)d_in[0];
  const float* v  = (const float*)d_in[1];
  float* out      = (float*)d_out;

  unsigned*      amax_bits = (unsigned*)d_ws;
  unsigned char* vq        = (unsigned char*)d_ws + 256;
  size_t vq_bytes = (size_t)BH_ * NKS * VKS_B;            // 8 MB
  size_t need_full = 256 + vq_bytes;

  init_kernel<<<1, 64, 0, stream>>>(amax_bits);

  long n4a = (long)B_ * H_ * T_ * S_ / 4;
  long n4v = (long)B_ * H_ * S_ * D_ / 4;
  amax2_kernel<<<2304, 256, 0, stream>>>(aw, n4a, v, n4v, amax_bits);

  if (ws_size >= need_full) {
    quantv_ldsorder_kernel<<<BH_ * NKS, 256, 0, stream>>>(v, vq, amax_bits);
    gemm_lds_kernel<<<BH_ * 32, 256, 0, stream>>>(aw, vq, out, amax_bits);
  } else {
    gemm_fused_kernel<<<B_ * H_ * (T_ / 64), 256, 0, stream>>>(aw, v, out,
                                                               amax_bits);
  }
}